// Round 3
// baseline (127.351 us; speedup 1.0000x reference)
//
#include <hip/hip_runtime.h>
#include <math.h>

#define Bq 16
#define Tq 81
#define Dq 128
#define Hq 8
#define BT (Bq*Tq)          // 1296
#define BTD (Bq*Tq*Dq)      // 165888 (out region 0)
#define PS 84               // padded s-stride of P rows in LDS
// ws layout (floats). Q: [b][h][t][d] f32; V: [b][h][s][d] bf16 in V_OFF.
#define P_SZ   (Bq*Tq*Hq*PS)
#define QV_SZ  (BT*Hq*Dq)
#define P_OFF  0
#define Q_OFF  (P_OFF + P_SZ)
#define V_OFF  (Q_OFF + QV_SZ)

#define LSTR 136            // k_qkv LDS row stride (ushorts): 16B-aligned rows

#define TCH 3               // t-rows per k23 block (81 = 27*3, no tail)
#define NCH 27

typedef __attribute__((ext_vector_type(8))) short short8;
typedef __attribute__((ext_vector_type(4))) float f32x4;

__device__ __forceinline__ float l1_4(const float4 q, const float4 k) {
    return fabsf(q.x - k.x) + fabsf(q.y - k.y) + fabsf(q.z - k.z) + fabsf(q.w - k.w);
}
__device__ __forceinline__ int imin(int a, int b) { return a < b ? a : b; }
__device__ __forceinline__ unsigned short f2bf(float f) {   // RNE f32 -> bf16
    unsigned u = __float_as_uint(f);
    u += 0x7fffu + ((u >> 16) & 1u);
    return (unsigned short)(u >> 16);
}
__device__ __forceinline__ float bf2f(unsigned short s) {
    return __uint_as_float((unsigned)s << 16);
}
// hoist a wave-uniform pointer to SGPRs (HK technique: readfirstlane bases)
__device__ __forceinline__ const float* rfl_ptr(const float* p) {
    unsigned long long u = (unsigned long long)p;
    const unsigned lo = __builtin_amdgcn_readfirstlane((unsigned)u);
    const unsigned hi = __builtin_amdgcn_readfirstlane((unsigned)(u >> 32));
    return (const float*)(((unsigned long long)hi << 32) | lo);
}

// ---------------------------------------------------------------------------
// K1: QKV GEMM via bf16 MFMA 16x16x32. grid (21, 32), 256 thr = 4 waves.
// Unchanged (verified).
// ---------------------------------------------------------------------------
__global__ __launch_bounds__(256) void k_qkv_mfma(
    const float* __restrict__ x, const float* __restrict__ wqkv,
    const float* __restrict__ bias, const float* __restrict__ he,
    float* __restrict__ Qo, unsigned short* __restrict__ Vb)
{
    __shared__ unsigned short xs[64 * LSTR];    // 17.4 KB
    __shared__ unsigned short wsh[64 * LSTR];   // 17.4 KB
    const int tid = threadIdx.x;
    const int w = tid >> 6, lane = tid & 63;
    const int ln = lane & 15, quad = lane >> 4;
    const int r0 = blockIdx.x * 64;               // m-row base (bx 0..20)
    const int n0 = blockIdx.y * 64;               // W-row base
    const int h  = blockIdx.y >> 2;
    const int isV = (blockIdx.y >> 1) & 1;
    const int c0 = (blockIdx.y & 1) * 64;

    #pragma unroll
    for (int i = 0; i < 8; ++i) {
        const int idx = tid + i * 256;            // 0..2047
        const int r = idx >> 5, c4 = idx & 31;
        const int gr = imin(r0 + r, BT - 1);      // clamp tail rows
        const float4 v = *(const float4*)(x + (size_t)gr * Dq + c4 * 4);
        ushort4 o;
        o.x = f2bf(v.x); o.y = f2bf(v.y); o.z = f2bf(v.z); o.w = f2bf(v.w);
        *(ushort4*)(&xs[r * LSTR + c4 * 4]) = o;

        const float4 vw = *(const float4*)(wqkv + (size_t)(n0 + r) * Dq + c4 * 4);
        ushort4 ow;
        ow.x = f2bf(vw.x); ow.y = f2bf(vw.y); ow.z = f2bf(vw.z); ow.w = f2bf(vw.w);
        *(ushort4*)(&wsh[r * LSTR + c4 * 4]) = ow;
    }
    __syncthreads();

    const unsigned short* xa = xs + (w * 16 + ln) * LSTR + quad * 8;
    const unsigned short* wb = wsh + ln * LSTR + quad * 8;

    f32x4 acc[4];
    #pragma unroll
    for (int i = 0; i < 4; ++i) acc[i] = (f32x4){0.f, 0.f, 0.f, 0.f};

    #pragma unroll
    for (int kb = 0; kb < Dq; kb += 32) {
        const short8 af = *(const short8*)(xa + kb);
        #pragma unroll
        for (int nt = 0; nt < 4; ++nt) {
            const short8 bf = *(const short8*)(wb + nt * 16 * LSTR + kb);
            acc[nt] = __builtin_amdgcn_mfma_f32_16x16x32_bf16(af, bf, acc[nt], 0, 0, 0);
        }
    }

    const float scale = isV ? he[h] : 1.0f;
    const int gm0 = r0 + w * 16 + quad * 4;
    #pragma unroll
    for (int nt = 0; nt < 4; ++nt) {
        const float bn = bias[n0 + nt * 16 + ln];
        #pragma unroll
        for (int r = 0; r < 4; ++r) {
            const int gm = gm0 + r;
            if (gm < BT) {
                const int bb = gm / 81, tt = gm - bb * 81;
                const size_t o =
                    (((size_t)bb * Hq + h) * Tq + tt) * Dq + c0 + nt * 16 + ln;
                const float val = (acc[nt][r] + bn) * scale;
                if (isV) Vb[o] = f2bf(val);
                else     Qo[o] = val;
            }
        }
    }
}

// ---------------------------------------------------------------------------
// K23: scores + softmax (+ap) + PV + gelu + fanout + residual.
// grid (27, 16) = (t-chunk3, b), block 512 = 8 waves; wave w = head w.
// R3 changes vs R2 (theory: phase B LDS-issue-bound; q/wk broadcasts ~half
// of its LDS cycles; phase D VMEM-issue heavy):
//  - Ql/wkl staging DROPPED: q/wk read from global via readfirstlane-hoisted
//    uniform bases (scalar/L1 path, off the LDS pipe). LDS 57.9 -> 49.5 KB.
//  - B->C and C->D barriers removed (Pl is wave-private; single barrier after
//    C protects the xl->bo overlay).
//  - Phase D: lane = (d-quad, s-half); ushort4 V loads (VMEM issues/wave
//    81 -> 44); halves combined via shfl_xor(32). Pl pad s=81..83 zeroed in
//    phase C so the overhang chunk contributes 0.
// smem overlay (floats):
//   [0,10368)=xl (phases A..B) ; [0,3072)=bo, [4096,4480)=zs (phases D..F)
// ---------------------------------------------------------------------------
__global__ __launch_bounds__(512) void k_attn_out(
    const float* __restrict__ x, const float* __restrict__ Q,
    const float* __restrict__ wk, const float* __restrict__ msk,
    const unsigned short* __restrict__ Vb, const float* __restrict__ fw,
    const float* __restrict__ fb, float* __restrict__ out)
{
    __shared__ float smem[10368];            // 41.5 KB (overlaid)
    __shared__ float Pl[Hq][TCH][PS];        // 8.06 KB
    float* const xl  = smem;                 // [81][128], granule-swizzled
    float* const bo  = smem;                 // [8*3][128] overlay
    float* const zs  = smem + 4096;          // [3][128]  overlay

    const int tid = threadIdx.x;
    const int t0 = blockIdx.x * TCH, b = blockIdx.y;
    const int w = tid >> 6, lane = tid & 63;   // w = head

    // ---- Phase A: stage xl (16B-granule XOR swizzle) ----
    for (int idx = tid; idx < Tq * 32; idx += 512) {
        const int r = idx >> 5, g = idx & 31;
        const float4 v = *(const float4*)(x + (size_t)(b * Tq + r) * Dq + g * 4);
        *(float4*)(&xl[r * Dq + ((g ^ (r & 7)) << 2)]) = v;
    }
    __syncthreads();

    // ---- Phase B: L1-distance scores; q/wk via uniform global bases ----
    const float* wku = rfl_ptr(wk + (size_t)w * Dq);
    const float* qbu = rfl_ptr(Q + (((size_t)b * Hq + w) * Tq + t0) * Dq);

    float acc0[TCH];
    #pragma unroll
    for (int i = 0; i < TCH; ++i) acc0[i] = 0.f;
    {   // main: s = lane (0..63), all 3 t-rows
        const int s = lane;
        #pragma unroll 2
        for (int g = 0; g < 32; ++g) {
            const float4 wv = *(const float4*)(wku + g * 4);          // uniform
            float4 k0 = *(const float4*)(&xl[s * Dq + ((g ^ (s & 7)) << 2)]);
            k0.x *= wv.x; k0.y *= wv.y; k0.z *= wv.z; k0.w *= wv.w;
            #pragma unroll
            for (int i = 0; i < TCH; ++i) {
                const float4 qv = *(const float4*)(qbu + i * Dq + g * 4); // unif
                acc0[i] += l1_4(qv, k0);
            }
        }
    }
    const float ns = -0.08838834764831845f;   // -1/sqrt(128)
    {   // tail: 51 cells (t, s=64+j), lanes 0..50
        if (lane < TCH * 17) {
            const int tt = lane / 17, j = lane - tt * 17;
            const int s = 64 + j;
            float a = 0.f;
            #pragma unroll 2
            for (int g = 0; g < 32; ++g) {
                const float4 wv = *(const float4*)(wku + g * 4);
                float4 kv = *(const float4*)(&xl[s * Dq + ((g ^ (s & 7)) << 2)]);
                kv.x *= wv.x; kv.y *= wv.y; kv.z *= wv.z; kv.w *= wv.w;
                const float4 qv = *(const float4*)(qbu + tt * Dq + g * 4);
                a += l1_4(qv, kv);
            }
            Pl[w][tt][s] = a * ns;            // stage raw tail scores
        }
    }
    // no barrier: Pl[w] is wave-private (same wave writes + reads)

    // ---- Phase C: wave softmax + P->LDS + fused ap (b==0) ----
    {
        const bool has1 = (lane < Tq - 64);   // 17 lanes own s=64..80
        const int s1 = 64 + lane;
        #pragma unroll
        for (int i = 0; i < TCH; ++i) {
            const float v0 = acc0[i] * ns;
            const float v1 = has1 ? Pl[w][i][s1] : -1e30f;
            float m = fmaxf(v0, v1);
            #pragma unroll
            for (int off = 32; off > 0; off >>= 1)
                m = fmaxf(m, __shfl_xor(m, off));
            const float e0 = __expf(v0 - m);
            const float e1 = has1 ? __expf(v1 - m) : 0.f;
            float ssum = e0 + e1;
            #pragma unroll
            for (int off = 32; off > 0; off >>= 1)
                ssum += __shfl_xor(ssum, off);
            const float rinv = 1.0f / ssum;
            const float* mrow = msk + ((size_t)w * Tq + (t0 + i)) * Tq;
            const float mv0 = mrow[lane];
            const float p0 = e0 * rinv * mv0;
            Pl[w][i][lane] = p0;
            if (b == 0)
                out[BTD + ((size_t)(t0 + i) * Tq + lane) * Hq + w] = p0 - 1.0f + mv0;
            if (has1) {
                const float mv1 = mrow[s1];
                const float p1 = e1 * rinv * mv1;
                Pl[w][i][s1] = p1;
                if (b == 0)
                    out[BTD + ((size_t)(t0 + i) * Tq + s1) * Hq + w] = p1 - 1.0f + mv1;
            }
            if (lane < 3) Pl[w][i][81 + lane] = 0.f;   // zero pad for phase D
        }
    }
    __syncthreads();   // required: phase D's bo overlays xl (still read in B)

    // ---- Phase D: PV einsum; lane=(d-quad, s-half); ushort4 V loads ----
    {
        const int d2 = lane & 31, sh = lane >> 5;
        const int d0 = d2 * 4;
        const unsigned short* vp = Vb + (((size_t)b * Hq + w) * Tq) * Dq + d0;
        float4 acc[TCH];
        #pragma unroll
        for (int t = 0; t < TCH; ++t) acc[t] = make_float4(0.f, 0.f, 0.f, 0.f);
        const int sb = sh * 44;
        const int nck = 11 - sh;              // sh=0: s 0..43; sh=1: s 44..83
        for (int c = 0; c < nck; ++c) {
            const int s0c = sb + c * 4;
            float4 p[TCH];
            #pragma unroll
            for (int t = 0; t < TCH; ++t)
                p[t] = *(const float4*)(&Pl[w][t][s0c]);   // 2-addr broadcast
            #pragma unroll
            for (int ss = 0; ss < 4; ++ss) {
                const int s = s0c + ss;       // 81..83 -> p=0 (pad)
                const ushort4 uv = *(const ushort4*)(vp + (size_t)s * Dq);
                const float vx = bf2f(uv.x), vy = bf2f(uv.y);
                const float vz = bf2f(uv.z), vw2 = bf2f(uv.w);
                #pragma unroll
                for (int t = 0; t < TCH; ++t) {
                    const float pv = ((const float*)&p[t])[ss];
                    acc[t].x = fmaf(pv, vx,  acc[t].x);
                    acc[t].y = fmaf(pv, vy,  acc[t].y);
                    acc[t].z = fmaf(pv, vz,  acc[t].z);
                    acc[t].w = fmaf(pv, vw2, acc[t].w);
                }
            }
        }
        #pragma unroll
        for (int t = 0; t < TCH; ++t) {       // combine the two s-halves
            acc[t].x += __shfl_xor(acc[t].x, 32);
            acc[t].y += __shfl_xor(acc[t].y, 32);
            acc[t].z += __shfl_xor(acc[t].z, 32);
            acc[t].w += __shfl_xor(acc[t].w, 32);
        }
        if (sh == 0) {
            #pragma unroll
            for (int t = 0; t < TCH; ++t)
                *(float4*)(&bo[(w * TCH + t) * Dq + d0]) = acc[t];
        }
    }
    __syncthreads();

    // ---- Phase E: 8-way head reduce + quick-gelu ----
    for (int idx = tid; idx < TCH * Dq; idx += 512) {   // 3t x 128d
        const int t = idx >> 7, d = idx & 127;
        float s = 0.f;
        #pragma unroll
        for (int ww = 0; ww < 8; ++ww) s += bo[(ww * TCH + t) * Dq + d];
        const float tt2 = s + 4.0f;
        const float sg = 1.0f / (1.0f + __expf(-1.702f * tt2));
        zs[t * Dq + d] = tt2 * sg - 4.0f;
    }
    __syncthreads();

    // ---- Phase F: fanout + bias + residual (384 threads, 1 row each) ----
    {
        const int n = tid & 127, tg = tid >> 7;   // tg 0..3
        if (tg < TCH) {
            const float* fwr = fw + (size_t)n * Dq;
            float a0 = 0.f;
            #pragma unroll 8
            for (int k4 = 0; k4 < 32; ++k4) {
                const float4 w4 = *(const float4*)(fwr + k4 * 4);
                const float4 z0 = *(const float4*)(&zs[tg * Dq + k4 * 4]);
                a0 += z0.x * w4.x + z0.y * w4.y + z0.z * w4.z + z0.w * w4.w;
            }
            const size_t o = ((size_t)b * Tq + t0 + tg) * Dq + n;
            out[o] = x[o] + a0 + fb[n];
        }
    }
}

extern "C" void kernel_launch(void* const* d_in, const int* in_sizes, int n_in,
                              void* d_out, int out_size, void* d_ws, size_t ws_size,
                              hipStream_t stream) {
    const float* x        = (const float*)d_in[0];
    const float* msk      = (const float*)d_in[1];
    const float* wqkv_w   = (const float*)d_in[2];
    const float* wqkv_b   = (const float*)d_in[3];
    const float* wk_w     = (const float*)d_in[4];
    const float* fanout_w = (const float*)d_in[5];
    const float* fanout_b = (const float*)d_in[6];
    const float* he       = (const float*)d_in[7];
    float* out = (float*)d_out;
    float* ws  = (float*)d_ws;

    float* Q  = ws + Q_OFF;
    unsigned short* Vb = (unsigned short*)(ws + V_OFF);

    k_qkv_mfma<<<dim3(21, 32), 256, 0, stream>>>(x, wqkv_w, wqkv_b, he, Q, Vb);
    k_attn_out<<<dim3(NCH, 16), 512, 0, stream>>>(x, Q, wk_w, msk, Vb,
                                                  fanout_w, fanout_b, out);
}

// Round 5
// 115.321 us; speedup vs baseline: 1.1043x; 1.1043x over previous
//
#include <hip/hip_runtime.h>
#include <math.h>

#define Bq 16
#define Tq 81
#define Dq 128
#define Hq 8
#define BT (Bq*Tq)          // 1296
#define BTD (Bq*Tq*Dq)      // 165888 (out region 0)
#define PS 84               // padded s-stride of P rows in LDS
// ws layout (floats). Q: [b][h][t][d] f32; V: [b][h][s][d] bf16 in V_OFF.
#define P_SZ   (Bq*Tq*Hq*PS)
#define QV_SZ  (BT*Hq*Dq)
#define P_OFF  0
#define Q_OFF  (P_OFF + P_SZ)
#define V_OFF  (Q_OFF + QV_SZ)

#define LSTR 136            // k_qkv LDS row stride (ushorts): 16B-aligned rows

#define TCH 3               // t-rows per k23 block (81 = 27*3, no tail)
#define NCH 27

// k_attn_out smem float-offsets: xlb(bf16 x) [0,5184) | Ql [5184,8256) |
// wkl [8256,9280). Overlay after scores: bo [0,3072) | zs [3328,3712).
#define SMEMF   9280
#define QL_OFF  5184
#define WKL_OFF 8256
#define ZS_OFF  3328

typedef __attribute__((ext_vector_type(8))) short short8;
typedef __attribute__((ext_vector_type(4))) float f32x4;

__device__ __forceinline__ float l1_4(const float4 q, const float4 k) {
    return fabsf(q.x - k.x) + fabsf(q.y - k.y) + fabsf(q.z - k.z) + fabsf(q.w - k.w);
}
__device__ __forceinline__ int imin(int a, int b) { return a < b ? a : b; }
__device__ __forceinline__ unsigned short f2bf(float f) {   // RNE f32 -> bf16
    unsigned u = __float_as_uint(f);
    u += 0x7fffu + ((u >> 16) & 1u);
    return (unsigned short)(u >> 16);
}
__device__ __forceinline__ float bf2f(unsigned short s) {
    return __uint_as_float((unsigned)s << 16);
}
__device__ __forceinline__ float bfu_lo(unsigned u) {   // low bf16 of dword
    return __uint_as_float(u << 16);
}
__device__ __forceinline__ float bfu_hi(unsigned u) {   // high bf16 of dword
    return __uint_as_float(u & 0xffff0000u);
}

// ---------------------------------------------------------------------------
// K1: QKV GEMM via bf16 MFMA 16x16x32. grid (21, 32), 256 thr = 4 waves.
// Unchanged (verified).
// ---------------------------------------------------------------------------
__global__ __launch_bounds__(256) void k_qkv_mfma(
    const float* __restrict__ x, const float* __restrict__ wqkv,
    const float* __restrict__ bias, const float* __restrict__ he,
    float* __restrict__ Qo, unsigned short* __restrict__ Vb)
{
    __shared__ unsigned short xs[64 * LSTR];    // 17.4 KB
    __shared__ unsigned short wsh[64 * LSTR];   // 17.4 KB
    const int tid = threadIdx.x;
    const int w = tid >> 6, lane = tid & 63;
    const int ln = lane & 15, quad = lane >> 4;
    const int r0 = blockIdx.x * 64;               // m-row base (bx 0..20)
    const int n0 = blockIdx.y * 64;               // W-row base
    const int h  = blockIdx.y >> 2;
    const int isV = (blockIdx.y >> 1) & 1;
    const int c0 = (blockIdx.y & 1) * 64;

    #pragma unroll
    for (int i = 0; i < 8; ++i) {
        const int idx = tid + i * 256;            // 0..2047
        const int r = idx >> 5, c4 = idx & 31;
        const int gr = imin(r0 + r, BT - 1);      // clamp tail rows
        const float4 v = *(const float4*)(x + (size_t)gr * Dq + c4 * 4);
        ushort4 o;
        o.x = f2bf(v.x); o.y = f2bf(v.y); o.z = f2bf(v.z); o.w = f2bf(v.w);
        *(ushort4*)(&xs[r * LSTR + c4 * 4]) = o;

        const float4 vw = *(const float4*)(wqkv + (size_t)(n0 + r) * Dq + c4 * 4);
        ushort4 ow;
        ow.x = f2bf(vw.x); ow.y = f2bf(vw.y); ow.z = f2bf(vw.z); ow.w = f2bf(vw.w);
        *(ushort4*)(&wsh[r * LSTR + c4 * 4]) = ow;
    }
    __syncthreads();

    const unsigned short* xa = xs + (w * 16 + ln) * LSTR + quad * 8;
    const unsigned short* wb = wsh + ln * LSTR + quad * 8;

    f32x4 acc[4];
    #pragma unroll
    for (int i = 0; i < 4; ++i) acc[i] = (f32x4){0.f, 0.f, 0.f, 0.f};

    #pragma unroll
    for (int kb = 0; kb < Dq; kb += 32) {
        const short8 af = *(const short8*)(xa + kb);
        #pragma unroll
        for (int nt = 0; nt < 4; ++nt) {
            const short8 bf = *(const short8*)(wb + nt * 16 * LSTR + kb);
            acc[nt] = __builtin_amdgcn_mfma_f32_16x16x32_bf16(af, bf, acc[nt], 0, 0, 0);
        }
    }

    const float scale = isV ? he[h] : 1.0f;
    const int gm0 = r0 + w * 16 + quad * 4;
    #pragma unroll
    for (int nt = 0; nt < 4; ++nt) {
        const float bn = bias[n0 + nt * 16 + ln];
        #pragma unroll
        for (int r = 0; r < 4; ++r) {
            const int gm = gm0 + r;
            if (gm < BT) {
                const int bb = gm / 81, tt = gm - bb * 81;
                const size_t o =
                    (((size_t)bb * Hq + h) * Tq + tt) * Dq + c0 + nt * 16 + ln;
                const float val = (acc[nt][r] + bn) * scale;
                if (isV) Vb[o] = f2bf(val);
                else     Qo[o] = val;
            }
        }
    }
}

// ---------------------------------------------------------------------------
// K23: scores + softmax (+ap) + PV + gelu + fanout + residual.
// grid (27, 16) = (t-chunk3, b), block 512 = 8 waves; wave w = head w.
// R4 (rerun; R4's bench was an infra failure, kernel never executed):
// revert R3's SMEM q/wk loads (s_load shares lgkmcnt with ds_read and
// returns OOO -> forced lgkmcnt(0) drains serialized the score loop; -12us).
// Back to R2 structure (Ql/wkl staged in LDS, R2 barriers, R2 phase D) with
// ONE change: the x tile is stored in LDS as bf16 (ushort), 16B granules of
// 8 values, same XOR swizzle. Effects:
//  - LDS 66 -> 45.2 KB => 3 blocks/CU (was 2): +50% waves for latency hiding
//    (k_attn_out was latency-bound: VALUBusy 26%, Occ 26%, HBM 4%).
//  - phase B per-lane ds_read count halves (b128 now covers 8 d-values).
// Numerics: q already has bf16-level error (MFMA QKV); bf16 K adds symmetric
// ~2^-9 rel error; score error ~3e-3 pre-softmax -> negligible in P/out.
// NOTE: phase-B bank "conflicts" (~1M in R3) are 8-way quad aliasing at the
// b128 bandwidth floor (64 lanes x 16B = 8 LDS cycles min) — not a real cost.
// ---------------------------------------------------------------------------
__global__ __launch_bounds__(512) void k_attn_out(
    const float* __restrict__ x, const float* __restrict__ Q,
    const float* __restrict__ wk, const float* __restrict__ msk,
    const unsigned short* __restrict__ Vb, const float* __restrict__ fw,
    const float* __restrict__ fb, float* __restrict__ out)
{
    __shared__ float smem[SMEMF];            // 37.1 KB (overlaid)
    __shared__ float Pl[Hq][TCH][PS];        // 8.06 KB
    unsigned short* const xlb = (unsigned short*)smem;   // [81][128] bf16, swz
    float* const Ql  = smem + QL_OFF;        // [8][3][128]
    float* const wkl = smem + WKL_OFF;       // [8][128]
    float* const bo  = smem;                 // [8*3][128] overlay (phase D..E)
    float* const zs  = smem + ZS_OFF;        // [3][128]  overlay (phase E..F)

    const int tid = threadIdx.x;
    const int t0 = blockIdx.x * TCH, b = blockIdx.y;
    const int w = tid >> 6, lane = tid & 63;   // w = head

    // ---- Phase A: stage xlb (bf16, 16B-granule XOR swizzle) + Ql + wkl ----
    for (int idx = tid; idx < Tq * 16; idx += 512) {     // 1296 granules
        const int r = idx >> 4, g8 = idx & 15;
        const float* src = x + (size_t)(b * Tq + r) * Dq + g8 * 8;
        const float4 a = *(const float4*)(src);
        const float4 c = *(const float4*)(src + 4);
        uint4 o;
        o.x = (unsigned)f2bf(a.x) | ((unsigned)f2bf(a.y) << 16);
        o.y = (unsigned)f2bf(a.z) | ((unsigned)f2bf(a.w) << 16);
        o.z = (unsigned)f2bf(c.x) | ((unsigned)f2bf(c.y) << 16);
        o.w = (unsigned)f2bf(c.z) | ((unsigned)f2bf(c.w) << 16);
        *(uint4*)(&xlb[r * Dq + ((g8 ^ (r & 7)) << 3)]) = o;
    }
    for (int idx = tid; idx < Hq * TCH * 32; idx += 512) {   // 768 float4
        const int row = idx >> 5, g = idx & 31;              // row = h*3+i
        const int h = row / TCH, i = row - h * TCH;
        const float4 v =
            *(const float4*)(Q + (((size_t)b * Hq + h) * Tq + t0 + i) * Dq + g * 4);
        *(float4*)(&Ql[row * Dq + g * 4]) = v;
    }
    if (tid < 256) {                                         // 8*128 floats
        const float4 v = *(const float4*)(wk + tid * 4);
        *(float4*)(&wkl[tid * 4]) = v;
    }
    __syncthreads();

    // ---- Phase B: L1-distance scores, all-LDS operands, bf16 K ----
    const float* wkw = wkl + w * Dq;
    const float* qb  = Ql + w * TCH * Dq;
    float acc0[TCH];
    #pragma unroll
    for (int i = 0; i < TCH; ++i) acc0[i] = 0.f;
    {   // main: s = lane (0..63), all 3 t-rows
        const int s = lane;
        const unsigned short* xrow = xlb + s * Dq;
        const int sx = (s & 7) << 3;
        #pragma unroll 4
        for (int g8 = 0; g8 < 16; ++g8) {
            const uint4 kk = *(const uint4*)(xrow + (((g8 << 3) ^ sx)));
            const float4 wv0 = *(const float4*)(wkw + g8 * 8);
            const float4 wv1 = *(const float4*)(wkw + g8 * 8 + 4);
            float4 k0, k1;
            k0.x = bfu_lo(kk.x) * wv0.x; k0.y = bfu_hi(kk.x) * wv0.y;
            k0.z = bfu_lo(kk.y) * wv0.z; k0.w = bfu_hi(kk.y) * wv0.w;
            k1.x = bfu_lo(kk.z) * wv1.x; k1.y = bfu_hi(kk.z) * wv1.y;
            k1.z = bfu_lo(kk.w) * wv1.z; k1.w = bfu_hi(kk.w) * wv1.w;
            #pragma unroll
            for (int i = 0; i < TCH; ++i) {
                const float4 q0 = *(const float4*)(qb + i * Dq + g8 * 8);
                const float4 q1 = *(const float4*)(qb + i * Dq + g8 * 8 + 4);
                acc0[i] += l1_4(q0, k0) + l1_4(q1, k1);
            }
        }
    }
    const float ns = -0.08838834764831845f;   // -1/sqrt(128)
    {   // tail: 51 cells (t, s=64+j), lanes 0..50
        if (lane < TCH * 17) {
            const int tt = lane / 17, j = lane - tt * 17;
            const int s = 64 + j;
            const unsigned short* xrow = xlb + s * Dq;
            const int sx = (s & 7) << 3;
            float a = 0.f;
            #pragma unroll 4
            for (int g8 = 0; g8 < 16; ++g8) {
                const uint4 kk = *(const uint4*)(xrow + (((g8 << 3) ^ sx)));
                const float4 wv0 = *(const float4*)(wkw + g8 * 8);
                const float4 wv1 = *(const float4*)(wkw + g8 * 8 + 4);
                float4 k0, k1;
                k0.x = bfu_lo(kk.x) * wv0.x; k0.y = bfu_hi(kk.x) * wv0.y;
                k0.z = bfu_lo(kk.y) * wv0.z; k0.w = bfu_hi(kk.y) * wv0.w;
                k1.x = bfu_lo(kk.z) * wv1.x; k1.y = bfu_hi(kk.z) * wv1.y;
                k1.z = bfu_lo(kk.w) * wv1.z; k1.w = bfu_hi(kk.w) * wv1.w;
                const float4 q0 = *(const float4*)(qb + tt * Dq + g8 * 8);
                const float4 q1 = *(const float4*)(qb + tt * Dq + g8 * 8 + 4);
                a += l1_4(q0, k0) + l1_4(q1, k1);
            }
            Pl[w][tt][s] = a * ns;            // stage raw tail scores
        }
    }
    __syncthreads();

    // ---- Phase C: wave softmax + P->LDS + fused ap (b==0) ----
    {
        const bool has1 = (lane < Tq - 64);   // 17 lanes own s=64..80
        const int s1 = 64 + lane;
        #pragma unroll
        for (int i = 0; i < TCH; ++i) {
            const float v0 = acc0[i] * ns;
            const float v1 = has1 ? Pl[w][i][s1] : -1e30f;
            float m = fmaxf(v0, v1);
            #pragma unroll
            for (int off = 32; off > 0; off >>= 1)
                m = fmaxf(m, __shfl_xor(m, off));
            const float e0 = __expf(v0 - m);
            const float e1 = has1 ? __expf(v1 - m) : 0.f;
            float ssum = e0 + e1;
            #pragma unroll
            for (int off = 32; off > 0; off >>= 1)
                ssum += __shfl_xor(ssum, off);
            const float rinv = 1.0f / ssum;
            const float* mrow = msk + ((size_t)w * Tq + (t0 + i)) * Tq;
            const float mv0 = mrow[lane];
            const float p0 = e0 * rinv * mv0;
            Pl[w][i][lane] = p0;
            if (b == 0)
                out[BTD + ((size_t)(t0 + i) * Tq + lane) * Hq + w] = p0 - 1.0f + mv0;
            if (has1) {
                const float mv1 = mrow[s1];
                const float p1 = e1 * rinv * mv1;
                Pl[w][i][s1] = p1;
                if (b == 0)
                    out[BTD + ((size_t)(t0 + i) * Tq + s1) * Hq + w] = p1 - 1.0f + mv1;
            }
        }
    }
    __syncthreads();   // protects xlb -> bo overlay

    // ---- Phase D: PV einsum, bf16 V, s blocked by 4 (R2 verbatim) ----
    {
        const int d0 = lane * 2;
        float2 acc[TCH];
        #pragma unroll
        for (int i = 0; i < TCH; ++i) acc[i] = make_float2(0.f, 0.f);
        const unsigned short* vp = Vb + (((size_t)b * Hq + w) * Tq) * Dq + d0;
        for (int s4 = 0; s4 < 20; ++s4) {
            float4 p[TCH];
            #pragma unroll
            for (int t = 0; t < TCH; ++t)
                p[t] = *(const float4*)(&Pl[w][t][s4 * 4]);
            #pragma unroll
            for (int ss = 0; ss < 4; ++ss) {
                const int s = s4 * 4 + ss;
                const ushort2 uv = *(const ushort2*)(vp + (size_t)s * Dq);
                const float vx = bf2f(uv.x), vy = bf2f(uv.y);
                #pragma unroll
                for (int t = 0; t < TCH; ++t) {
                    const float pv = ((const float*)&p[t])[ss];
                    acc[t].x = fmaf(pv, vx, acc[t].x);
                    acc[t].y = fmaf(pv, vy, acc[t].y);
                }
            }
        }
        {   // tail s = 80
            const ushort2 uv = *(const ushort2*)(vp + (size_t)80 * Dq);
            const float vx = bf2f(uv.x), vy = bf2f(uv.y);
            #pragma unroll
            for (int t = 0; t < TCH; ++t) {
                const float pv = Pl[w][t][80];
                acc[t].x = fmaf(pv, vx, acc[t].x);
                acc[t].y = fmaf(pv, vy, acc[t].y);
            }
        }
        #pragma unroll
        for (int t = 0; t < TCH; ++t) {
            bo[(w * TCH + t) * Dq + d0]     = acc[t].x;
            bo[(w * TCH + t) * Dq + d0 + 1] = acc[t].y;
        }
    }
    __syncthreads();

    // ---- Phase E: 8-way head reduce + quick-gelu ----
    for (int idx = tid; idx < TCH * Dq; idx += 512) {   // 3t x 128d
        const int t = idx >> 7, d = idx & 127;
        float s = 0.f;
        #pragma unroll
        for (int ww = 0; ww < 8; ++ww) s += bo[(ww * TCH + t) * Dq + d];
        const float tt2 = s + 4.0f;
        const float sg = 1.0f / (1.0f + __expf(-1.702f * tt2));
        zs[t * Dq + d] = tt2 * sg - 4.0f;
    }
    __syncthreads();

    // ---- Phase F: fanout + bias + residual (384 threads, 1 row each) ----
    {
        const int n = tid & 127, tg = tid >> 7;   // tg 0..3
        if (tg < TCH) {
            const float* fwr = fw + (size_t)n * Dq;
            float a0 = 0.f;
            #pragma unroll 8
            for (int k4 = 0; k4 < 32; ++k4) {
                const float4 w4 = *(const float4*)(fwr + k4 * 4);
                const float4 z0 = *(const float4*)(&zs[tg * Dq + k4 * 4]);
                a0 += z0.x * w4.x + z0.y * w4.y + z0.z * w4.z + z0.w * w4.w;
            }
            const size_t o = ((size_t)b * Tq + t0 + tg) * Dq + n;
            out[o] = x[o] + a0 + fb[n];
        }
    }
}

extern "C" void kernel_launch(void* const* d_in, const int* in_sizes, int n_in,
                              void* d_out, int out_size, void* d_ws, size_t ws_size,
                              hipStream_t stream) {
    const float* x        = (const float*)d_in[0];
    const float* msk      = (const float*)d_in[1];
    const float* wqkv_w   = (const float*)d_in[2];
    const float* wqkv_b   = (const float*)d_in[3];
    const float* wk_w     = (const float*)d_in[4];
    const float* fanout_w = (const float*)d_in[5];
    const float* fanout_b = (const float*)d_in[6];
    const float* he       = (const float*)d_in[7];
    float* out = (float*)d_out;
    float* ws  = (float*)d_ws;

    float* Q  = ws + Q_OFF;
    unsigned short* Vb = (unsigned short*)(ws + V_OFF);

    k_qkv_mfma<<<dim3(21, 32), 256, 0, stream>>>(x, wqkv_w, wqkv_b, he, Q, Vb);
    k_attn_out<<<dim3(NCH, 16), 512, 0, stream>>>(x, Q, wk_w, msk, Vb,
                                                  fanout_w, fanout_b, out);
}

// Round 7
// 111.536 us; speedup vs baseline: 1.1418x; 1.0339x over previous
//
#include <hip/hip_runtime.h>
#include <math.h>

#define Bq 16
#define Tq 81
#define Dq 128
#define Hq 8
#define BT (Bq*Tq)          // 1296
#define BTD (Bq*Tq*Dq)      // 165888 (out region 0)
#define PS 84               // padded s-stride of P row in LDS
// ws layout (floats). Q: [b][h][t][d] f32; V: [b][h][s][d] bf16 in V_OFF.
#define P_SZ   (Bq*Tq*Hq*PS)
#define QV_SZ  (BT*Hq*Dq)
#define P_OFF  0
#define Q_OFF  (P_OFF + P_SZ)
#define V_OFF  (Q_OFF + QV_SZ)

#define LSTR 136            // k_qkv LDS row stride (ushorts): 16B-aligned rows

typedef __attribute__((ext_vector_type(8))) short short8;
typedef __attribute__((ext_vector_type(4))) float f32x4;
typedef _Float16 h2 __attribute__((ext_vector_type(2)));

__device__ __forceinline__ int imin(int a, int b) { return a < b ? a : b; }
__device__ __forceinline__ unsigned short f2bf(float f) {   // RNE f32 -> bf16
    unsigned u = __float_as_uint(f);
    u += 0x7fffu + ((u >> 16) & 1u);
    return (unsigned short)(u >> 16);
}
__device__ __forceinline__ float bf2f(unsigned short s) {
    return __uint_as_float((unsigned)s << 16);
}
__device__ __forceinline__ unsigned pk2h(float a, float b) {  // 2xf32 -> packed f16
    h2 v; v[0] = (_Float16)a; v[1] = (_Float16)b;
    return *(unsigned*)&v;
}
// l1 step on 2 elems: d = q - x*w (v_pk_fma), |d| (v_and), f32 acc (v_dot2)
__device__ __forceinline__ float l1h(unsigned qv, unsigned xv, unsigned wv, float acc) {
    const h2 q = *(const h2*)&qv, xx = *(const h2*)&xv, ww = *(const h2*)&wv;
    h2 d = q - xx * ww;
    unsigned du = (*(unsigned*)&d) & 0x7fff7fffu;
    const h2 da = *(const h2*)&du;
#if __has_builtin(__builtin_amdgcn_fdot2)
    return __builtin_amdgcn_fdot2(da, (h2){(_Float16)1.f, (_Float16)1.f}, acc, false);
#else
    return acc + (float)da[0] + (float)da[1];
#endif
}

// ---------------------------------------------------------------------------
// K1: QKV GEMM via bf16 MFMA 16x16x32. grid (21, 32), 256 thr = 4 waves.
// Unchanged (verified).
// ---------------------------------------------------------------------------
__global__ __launch_bounds__(256) void k_qkv_mfma(
    const float* __restrict__ x, const float* __restrict__ wqkv,
    const float* __restrict__ bias, const float* __restrict__ he,
    float* __restrict__ Qo, unsigned short* __restrict__ Vb)
{
    __shared__ unsigned short xs[64 * LSTR];    // 17.4 KB
    __shared__ unsigned short wsh[64 * LSTR];   // 17.4 KB
    const int tid = threadIdx.x;
    const int w = tid >> 6, lane = tid & 63;
    const int ln = lane & 15, quad = lane >> 4;
    const int r0 = blockIdx.x * 64;               // m-row base (bx 0..20)
    const int n0 = blockIdx.y * 64;               // W-row base
    const int h  = blockIdx.y >> 2;
    const int isV = (blockIdx.y >> 1) & 1;
    const int c0 = (blockIdx.y & 1) * 64;

    #pragma unroll
    for (int i = 0; i < 8; ++i) {
        const int idx = tid + i * 256;            // 0..2047
        const int r = idx >> 5, c4 = idx & 31;
        const int gr = imin(r0 + r, BT - 1);      // clamp tail rows
        const float4 v = *(const float4*)(x + (size_t)gr * Dq + c4 * 4);
        ushort4 o;
        o.x = f2bf(v.x); o.y = f2bf(v.y); o.z = f2bf(v.z); o.w = f2bf(v.w);
        *(ushort4*)(&xs[r * LSTR + c4 * 4]) = o;

        const float4 vw = *(const float4*)(wqkv + (size_t)(n0 + r) * Dq + c4 * 4);
        ushort4 ow;
        ow.x = f2bf(vw.x); ow.y = f2bf(vw.y); ow.z = f2bf(vw.z); ow.w = f2bf(vw.w);
        *(ushort4*)(&wsh[r * LSTR + c4 * 4]) = ow;
    }
    __syncthreads();

    const unsigned short* xa = xs + (w * 16 + ln) * LSTR + quad * 8;
    const unsigned short* wb = wsh + ln * LSTR + quad * 8;

    f32x4 acc[4];
    #pragma unroll
    for (int i = 0; i < 4; ++i) acc[i] = (f32x4){0.f, 0.f, 0.f, 0.f};

    #pragma unroll
    for (int kb = 0; kb < Dq; kb += 32) {
        const short8 af = *(const short8*)(xa + kb);
        #pragma unroll
        for (int nt = 0; nt < 4; ++nt) {
            const short8 bf = *(const short8*)(wb + nt * 16 * LSTR + kb);
            acc[nt] = __builtin_amdgcn_mfma_f32_16x16x32_bf16(af, bf, acc[nt], 0, 0, 0);
        }
    }

    const float scale = isV ? he[h] : 1.0f;
    const int gm0 = r0 + w * 16 + quad * 4;
    #pragma unroll
    for (int nt = 0; nt < 4; ++nt) {
        const float bn = bias[n0 + nt * 16 + ln];
        #pragma unroll
        for (int r = 0; r < 4; ++r) {
            const int gm = gm0 + r;
            if (gm < BT) {
                const int bb = gm / 81, tt = gm - bb * 81;
                const size_t o =
                    (((size_t)bb * Hq + h) * Tq + tt) * Dq + c0 + nt * 16 + ln;
                const float val = (acc[nt][r] + bn) * scale;
                if (isV) Vb[o] = f2bf(val);
                else     Qo[o] = val;
            }
        }
    }
}

// ---------------------------------------------------------------------------
// K23: scores + softmax (+ap) + PV + gelu + fanout + residual.
// R6 (rerun; R6's bench was a GPU-acquisition timeout, kernel never ran):
// grid (81, 16) = (t, b) = 1296 blocks, block 512 = 8 waves; wave = head.
// Post-mortem R5: k_attn_out latency-bound NOT VALU-bound (VALUBusy 34%,
// Occ 28%). Root cause: grid 432 = 1.69x256 CUs -> half the CUs carry 2
// blocks (2x time) at only 2-4 waves/SIMD. Fixes:
//  - TCH 3 -> 1: 1296 blocks = 5.06x256 (imbalance 1.2 vs 2.0); LDS ~28 KB
//    -> 4 resident blocks/CU = 32 waves/CU (full capacity).
//  - f16-packed scores: x/Q/wk staged as f16; per-2-elems the l1 core is
//    v_pk_fma_f16 (k=x*wk fused) + v_and (abs) + v_dot2_f32_f16 (f32 acc):
//    VALU per g8 16 -> 12, LDS reads per g8 9 -> 3. f16 staging is MORE
//    precise than R5's bf16 x (10-bit vs 8-bit mantissa); acc stays f32.
//  - tail s=64..80 owned by lanes 0..16 = the softmax has1 lanes -> tail
//    scores stay in registers (no Pl staging round-trip).
// smem: xlh f16[81][128] swz (20.7 KB) | Qlh f16[8][128] | wklh f16[8][128]
//       | Pl f32[8][84]. Overlay after scores: bo[8][128] f32, zs[128] f32
//       on the xlh region.
// ---------------------------------------------------------------------------
__global__ __launch_bounds__(512) void k_attn_out(
    const float* __restrict__ x, const float* __restrict__ Q,
    const float* __restrict__ wk, const float* __restrict__ msk,
    const unsigned short* __restrict__ Vb, const float* __restrict__ fw,
    const float* __restrict__ fb, float* __restrict__ out)
{
    __shared__ unsigned short xlh[Tq * Dq];   // 20.7 KB f16, granule-swizzled
    __shared__ unsigned short Qlh[Hq * Dq];   // 2 KB f16
    __shared__ unsigned short wklh[Hq * Dq];  // 2 KB f16
    __shared__ float Pl[Hq][PS];              // 2.7 KB
    float* const bo = (float*)xlh;            // [8][128] overlay (D..E)
    float* const zs = (float*)xlh + 1024;     // [128]    overlay (E..F)

    const int tid = threadIdx.x;
    const int t0 = blockIdx.x, b = blockIdx.y;
    const int w = tid >> 6, lane = tid & 63;   // w = head

    // ---- Phase A: stage xlh (f16, 16B-granule XOR swizzle) + Qlh + wklh ----
    for (int idx = tid; idx < Tq * 16; idx += 512) {     // 1296 granules
        const int r = idx >> 4, g8 = idx & 15;
        const float* src = x + (size_t)(b * Tq + r) * Dq + g8 * 8;
        const float4 a = *(const float4*)(src);
        const float4 c = *(const float4*)(src + 4);
        uint4 o;
        o.x = pk2h(a.x, a.y); o.y = pk2h(a.z, a.w);
        o.z = pk2h(c.x, c.y); o.w = pk2h(c.z, c.w);
        *(uint4*)(&xlh[r * Dq + ((g8 ^ (r & 7)) << 3)]) = o;
    }
    if (tid < 128) {                                     // Q row t0, 8 heads
        const int hh = tid >> 4, g8 = tid & 15;
        const float* src = Q + (((size_t)b * Hq + hh) * Tq + t0) * Dq + g8 * 8;
        const float4 a = *(const float4*)(src);
        const float4 c = *(const float4*)(src + 4);
        uint4 o;
        o.x = pk2h(a.x, a.y); o.y = pk2h(a.z, a.w);
        o.z = pk2h(c.x, c.y); o.w = pk2h(c.z, c.w);
        *(uint4*)(&Qlh[hh * Dq + g8 * 8]) = o;
    }
    if (tid >= 256 && tid < 384) {                       // wk, 8 heads
        const int t2 = tid - 256;
        const int hh = t2 >> 4, g8 = t2 & 15;
        const float* src = wk + (size_t)hh * Dq + g8 * 8;
        const float4 a = *(const float4*)(src);
        const float4 c = *(const float4*)(src + 4);
        uint4 o;
        o.x = pk2h(a.x, a.y); o.y = pk2h(a.z, a.w);
        o.z = pk2h(c.x, c.y); o.w = pk2h(c.z, c.w);
        *(uint4*)(&wklh[hh * Dq + g8 * 8]) = o;
    }
    __syncthreads();

    // ---- Phase B: L1-distance scores, packed f16, f32 accumulate ----
    const unsigned short* wrow = wklh + w * Dq;
    const unsigned short* qrow = Qlh + w * Dq;
    const int sx = (lane & 7) << 3;           // (64+lane)&7 == lane&7
    float acc0 = 0.f, acc1 = 0.f;
    {   // main: s = lane
        const unsigned short* xrow = xlh + (size_t)lane * Dq;
        #pragma unroll 4
        for (int g8 = 0; g8 < 16; ++g8) {
            const uint4 kk = *(const uint4*)(xrow + ((g8 << 3) ^ sx));
            const uint4 wv = *(const uint4*)(wrow + (g8 << 3));
            const uint4 qq = *(const uint4*)(qrow + (g8 << 3));
            acc0 = l1h(qq.x, kk.x, wv.x, acc0);
            acc0 = l1h(qq.y, kk.y, wv.y, acc0);
            acc0 = l1h(qq.z, kk.z, wv.z, acc0);
            acc0 = l1h(qq.w, kk.w, wv.w, acc0);
        }
    }
    if (lane < Tq - 64) {   // tail: s = 64+lane on lanes 0..16 (softmax lanes)
        const unsigned short* xrow = xlh + (size_t)(64 + lane) * Dq;
        #pragma unroll 4
        for (int g8 = 0; g8 < 16; ++g8) {
            const uint4 kk = *(const uint4*)(xrow + ((g8 << 3) ^ sx));
            const uint4 wv = *(const uint4*)(wrow + (g8 << 3));
            const uint4 qq = *(const uint4*)(qrow + (g8 << 3));
            acc1 = l1h(qq.x, kk.x, wv.x, acc1);
            acc1 = l1h(qq.y, kk.y, wv.y, acc1);
            acc1 = l1h(qq.z, kk.z, wv.z, acc1);
            acc1 = l1h(qq.w, kk.w, wv.w, acc1);
        }
    }

    // ---- Phase C: wave softmax + P->LDS + fused ap (b==0) ----
    {
        const float ns = -0.08838834764831845f;   // -1/sqrt(128)
        const bool has1 = (lane < Tq - 64);
        const float v0 = acc0 * ns;
        const float v1 = has1 ? acc1 * ns : -1e30f;
        float m = fmaxf(v0, v1);
        #pragma unroll
        for (int off = 32; off > 0; off >>= 1)
            m = fmaxf(m, __shfl_xor(m, off));
        const float e0 = __expf(v0 - m);
        const float e1 = has1 ? __expf(v1 - m) : 0.f;
        float ssum = e0 + e1;
        #pragma unroll
        for (int off = 32; off > 0; off >>= 1)
            ssum += __shfl_xor(ssum, off);
        const float rinv = 1.0f / ssum;
        const float* mrow = msk + ((size_t)w * Tq + t0) * Tq;
        const float mv0 = mrow[lane];
        const float p0 = e0 * rinv * mv0;
        Pl[w][lane] = p0;
        if (b == 0)
            out[BTD + ((size_t)t0 * Tq + lane) * Hq + w] = p0 - 1.0f + mv0;
        if (has1) {
            const float mv1 = mrow[64 + lane];
            const float p1 = e1 * rinv * mv1;
            Pl[w][64 + lane] = p1;
            if (b == 0)
                out[BTD + ((size_t)t0 * Tq + 64 + lane) * Hq + w] = p1 - 1.0f + mv1;
        }
        if (lane < 3) Pl[w][81 + lane] = 0.f;     // zero pad (unused by D tail)
    }
    __syncthreads();   // all waves done reading xlh before bo overlay

    // ---- Phase D: PV einsum, bf16 V, s blocked by 4 ----
    {
        const int d0 = lane * 2;
        float2 acc = make_float2(0.f, 0.f);
        const unsigned short* vp = Vb + (((size_t)b * Hq + w) * Tq) * Dq + d0;
        for (int s4 = 0; s4 < 20; ++s4) {
            const float4 p = *(const float4*)(&Pl[w][s4 * 4]);
            #pragma unroll
            for (int ss = 0; ss < 4; ++ss) {
                const int s = s4 * 4 + ss;
                const ushort2 uv = *(const ushort2*)(vp + (size_t)s * Dq);
                const float pv = ((const float*)&p)[ss];
                acc.x = fmaf(pv, bf2f(uv.x), acc.x);
                acc.y = fmaf(pv, bf2f(uv.y), acc.y);
            }
        }
        {   // tail s = 80
            const ushort2 uv = *(const ushort2*)(vp + (size_t)80 * Dq);
            const float pv = Pl[w][80];
            acc.x = fmaf(pv, bf2f(uv.x), acc.x);
            acc.y = fmaf(pv, bf2f(uv.y), acc.y);
        }
        bo[w * Dq + d0]     = acc.x;
        bo[w * Dq + d0 + 1] = acc.y;
    }
    __syncthreads();

    // ---- Phase E: 8-way head reduce + quick-gelu (128 threads) ----
    if (tid < Dq) {
        float s = 0.f;
        #pragma unroll
        for (int ww = 0; ww < 8; ++ww) s += bo[ww * Dq + tid];
        const float tt2 = s + 4.0f;
        const float sg = 1.0f / (1.0f + __expf(-1.702f * tt2));
        zs[tid] = tt2 * sg - 4.0f;
    }
    __syncthreads();

    // ---- Phase F: fanout + bias + residual (128 threads, 1 n each) ----
    if (tid < Dq) {
        const int n = tid;
        const float* fwr = fw + (size_t)n * Dq;
        float a0 = 0.f;
        #pragma unroll 8
        for (int k4 = 0; k4 < 32; ++k4) {
            const float4 w4 = *(const float4*)(fwr + k4 * 4);
            const float4 z0 = *(const float4*)(&zs[k4 * 4]);
            a0 += z0.x * w4.x + z0.y * w4.y + z0.z * w4.z + z0.w * w4.w;
        }
        const size_t o = ((size_t)b * Tq + t0) * Dq + n;
        out[o] = x[o] + a0 + fb[n];
    }
}

extern "C" void kernel_launch(void* const* d_in, const int* in_sizes, int n_in,
                              void* d_out, int out_size, void* d_ws, size_t ws_size,
                              hipStream_t stream) {
    const float* x        = (const float*)d_in[0];
    const float* msk      = (const float*)d_in[1];
    const float* wqkv_w   = (const float*)d_in[2];
    const float* wqkv_b   = (const float*)d_in[3];
    const float* wk_w     = (const float*)d_in[4];
    const float* fanout_w = (const float*)d_in[5];
    const float* fanout_b = (const float*)d_in[6];
    const float* he       = (const float*)d_in[7];
    float* out = (float*)d_out;
    float* ws  = (float*)d_ws;

    float* Q  = ws + Q_OFF;
    unsigned short* Vb = (unsigned short*)(ws + V_OFF);

    k_qkv_mfma<<<dim3(21, 32), 256, 0, stream>>>(x, wqkv_w, wqkv_b, he, Q, Vb);
    k_attn_out<<<dim3(Tq, 16), 512, 0, stream>>>(x, Q, wk_w, msk, Vb,
                                                 fanout_w, fanout_b, out);
}